// Round 4
// baseline (146148.267 us; speedup 1.0000x reference)
//
#include <hip/hip_runtime.h>
#include <cstddef>

// Decoder: B=64, T=512, I=512, H1=256, H2=128, C=1024, M=80, L=2
// Round 4: (rt x kq) split-K grid -> weight slices L2-resident (1.5 MB/XCD);
// in-kernel split-K rendezvous (threadfence + per-rt counter, last block does
// the gate epilogue). Proj fused into res2 epilogue as per-rt partials;
// prenet of step t+1 reduces them into frame t. 4 kernels/step.

namespace {

constexpr int kB = 64, kT = 512, kI = 512, kH1 = 256, kH2 = 128, kC = 1024, kM = 80;

typedef __attribute__((ext_vector_type(8))) __bf16 bf16x8;
typedef __attribute__((ext_vector_type(4))) float f32x4;

__device__ __forceinline__ float sigm(float x) { return 1.0f / (1.0f + __expf(-x)); }
__device__ __forceinline__ float tanh_(float x) {
  float a = fabsf(x);
  float e = __expf(-2.0f * a);
  float r = (1.0f - e) / (1.0f + e);
  return copysignf(r, x);
}
__device__ __forceinline__ unsigned short f2bf(float x) {
  unsigned u = __builtin_bit_cast(unsigned, x);
  u += 0x7fffu + ((u >> 16) & 1u);   // RNE
  return (unsigned short)(u >> 16);
}
__device__ __forceinline__ bf16x8 asbf(uint4 v) { return __builtin_bit_cast(bf16x8, v); }
__device__ __forceinline__ f32x4 mfma16(bf16x8 a, bf16x8 b, f32x4 c) {
  return __builtin_amdgcn_mfma_f32_16x16x32_bf16(a, b, c, 0, 0, 0);
}

// ---- weight repack: fp32 [row][col] -> bf16 frag order [rt][ks][lane][8] ----
__global__ __launch_bounds__(256) void k_build_frags(
    const float* __restrict__ srcA, int ldA,
    const float* __restrict__ srcB, int ldB,
    int row0, int K1, int nks, int nrt, unsigned short* __restrict__ dst) {
  int idx = blockIdx.x * 256 + threadIdx.x;
  int lane = idx & 63;
  int ks = (idx >> 6) % nks;
  int rt = idx / (64 * nks);
  if (rt >= nrt) return;
  int row = row0 + rt * 16 + (lane & 15);
  int kk = ks * 32 + ((lane >> 4) & 3) * 8;
  const float* s = (kk < K1) ? (srcA + (size_t)row * ldA + kk)
                             : (srcB + (size_t)row * ldB + (kk - K1));
  unsigned short* d = dst + ((size_t)(rt * nks + ks) * 64 + lane) * 8;
#pragma unroll
  for (int j = 0; j < 8; ++j) d[j] = f2bf(s[j]);
}

__global__ __launch_bounds__(256) void k_transpose(const float* __restrict__ src,
    int R, int Ccols, float* __restrict__ dst) {
  int i = blockIdx.x * 256 + threadIdx.x;
  if (i >= R * Ccols) return;
  int r = i / Ccols, c = i % Ccols;
  dst[c * R + r] = src[r * Ccols + c];
}

// ---- prenet (+frame reduce of step t-1): one block per batch element --------
__global__ __launch_bounds__(256) void k_prenet(
    const float* __restrict__ inputs, int t,
    const float* __restrict__ pproj,       // [64rt][80][64] partials of frame t-1
    const float* __restrict__ proj_b,
    const float* __restrict__ w0t, const float* __restrict__ b0,
    const float* __restrict__ w1t, const float* __restrict__ b1,
    unsigned short* __restrict__ xcat0_cur,  // [64][1664]
    float* __restrict__ out_frames) {
  int b = blockIdx.x, tid = threadIdx.x;
  __shared__ float sfr[kM];
  __shared__ float sh[kH1];
  __shared__ float sred[160];
  const float* feat = inputs + ((size_t)b * kT + t) * kI;
  unsigned short* dst = xcat0_cur + (size_t)b * 1664;
  float2 f2v = *(const float2*)(feat + tid * 2);
  dst[tid * 2] = f2bf(f2v.x);
  dst[tid * 2 + 1] = f2bf(f2v.y);
  if (t > 0) {
    if (tid < 160) {
      int m = tid >> 1, half = tid & 1;
      const float* pp = pproj + ((size_t)(half * 32) * kM + m) * kB + b;
      float s = 0.0f;
#pragma unroll 8
      for (int r = 0; r < 32; ++r) s += pp[(size_t)r * kM * kB];
      sred[tid] = s;
    }
    __syncthreads();
    if (tid < kM) {
      float f = proj_b[tid] + sred[tid * 2] + sred[tid * 2 + 1];
      sfr[tid] = f;
      out_frames[(size_t)b * kT * kM + (size_t)(t - 1) * kM + tid] = f;
    }
  } else {
    if (tid < kM) sfr[tid] = 0.0f;
  }
  __syncthreads();
  float acc = b0[tid];
#pragma unroll 8
  for (int m = 0; m < kM; ++m) acc = fmaf(w0t[m * kH1 + tid], sfr[m], acc);
  sh[tid] = fmaxf(acc, 0.0f);
  __syncthreads();
  if (tid < kH2) {
    float a = b1[tid];
#pragma unroll 8
    for (int k = 0; k < kH1; ++k) a = fmaf(w1t[k * kH2 + tid], sh[k], a);
    dst[512 + tid] = f2bf(fmaxf(a, 0.0f));
  }
}

// ---- split-K GRU kernel -----------------------------------------------------
// grid = 64 rt * 4 kq, 512 threads (8 waves = 4 bt x 2 ksub).
// partials layout: [(rt*4+kq)][acc4][quad4][b64][4] fp32 (4096 floats / block).
template<int NKS, int NB, int BROW>
__global__ __launch_bounds__(512) void k_gru(
    const unsigned short* __restrict__ Ar, const unsigned short* __restrict__ Az,
    const unsigned short* __restrict__ An,
    const unsigned short* __restrict__ Bsrc,   // [64][BROW*8] bf16
    const float* __restrict__ h_old,           // [1024][64]
    const float* __restrict__ bih, const float* __restrict__ bhh,
    const float* __restrict__ xin_f32,         // nullable residual input
    float* __restrict__ h_new_f32,
    unsigned short* __restrict__ h_bf16, int strideA, int offA,
    unsigned short* __restrict__ x_bf16, int strideX,   // nullable
    float* __restrict__ xout_f32,                       // nullable
    float* __restrict__ partials, int* __restrict__ counters,
    const float* __restrict__ pw, float* __restrict__ pproj) {  // nullable pair
  constexpr int KQ = NKS / 4;
  constexpr int H0 = (KQ + 1) / 2;
  __shared__ float red[4096];
  __shared__ int sLast;
  int tid = threadIdx.x, lane = tid & 63, w = tid >> 6;
  int bt = w & 3, ksub = w >> 2, quad = lane >> 4;
  int rt = blockIdx.x >> 2, kq = blockIdx.x & 3;
  int b = bt * 16 + (lane & 15);
  const uint4* Bq = (const uint4*)Bsrc + (size_t)b * BROW + quad;
  const uint4* Arq = (const uint4*)Ar + (size_t)rt * NKS * 64 + lane;
  const uint4* Azq = (const uint4*)Az + (size_t)rt * NKS * 64 + lane;
  const uint4* Anq = (const uint4*)An + (size_t)rt * NKS * 64 + lane;
  f32x4 aR = {0.f, 0.f, 0.f, 0.f}, aZ = aR, aNI = aR, aNH = aR;
  int s0_ = kq * KQ + (ksub ? H0 : 0);
  int e0_ = kq * KQ + (ksub ? KQ : H0);
#pragma unroll 8
  for (int ks = s0_; ks < e0_; ++ks) {
    bf16x8 bv = asbf(Bq[ks * 4]);
    aR = mfma16(asbf(Arq[ks * 64]), bv, aR);
    aZ = mfma16(asbf(Azq[ks * 64]), bv, aZ);
    if (ks < NB) aNI = mfma16(asbf(Anq[ks * 64]), bv, aNI);
    else         aNH = mfma16(asbf(Anq[ks * 64]), bv, aNH);
  }
  if (ksub == 1) {
    *(f32x4*)&red[((bt * 4 + 0) * 64 + lane) * 4] = aR;
    *(f32x4*)&red[((bt * 4 + 1) * 64 + lane) * 4] = aZ;
    *(f32x4*)&red[((bt * 4 + 2) * 64 + lane) * 4] = aNI;
    *(f32x4*)&red[((bt * 4 + 3) * 64 + lane) * 4] = aNH;
  }
  __syncthreads();
  if (ksub == 0) {
    aR += *(f32x4*)&red[((bt * 4 + 0) * 64 + lane) * 4];
    aZ += *(f32x4*)&red[((bt * 4 + 1) * 64 + lane) * 4];
    aNI += *(f32x4*)&red[((bt * 4 + 2) * 64 + lane) * 4];
    aNH += *(f32x4*)&red[((bt * 4 + 3) * 64 + lane) * 4];
    float* pb = partials + (size_t)(rt * 4 + kq) * 4096;
    *(f32x4*)&pb[0 * 1024 + quad * 256 + b * 4] = aR;
    *(f32x4*)&pb[1 * 1024 + quad * 256 + b * 4] = aZ;
    *(f32x4*)&pb[2 * 1024 + quad * 256 + b * 4] = aNI;
    *(f32x4*)&pb[3 * 1024 + quad * 256 + b * 4] = aNH;
  }
  __threadfence();
  __syncthreads();
  if (tid == 0) sLast = (atomicAdd(&counters[rt], 1) == 3);
  __syncthreads();
  if (!sLast) return;
  __threadfence();
  if (tid == 0) counters[rt] = 0;

  // ---- epilogue (last-arriving block of this rt) ----
  int b2 = tid & 63, q2 = (tid >> 6) & 3, dup = tid >> 8;
  f32x4 sA = {0.f, 0.f, 0.f, 0.f}, sB = sA;
  const float* prt = partials + (size_t)rt * 4 * 4096;
#pragma unroll
  for (int k2 = 0; k2 < 4; ++k2) {
    const float* pp = prt + (size_t)k2 * 4096;
    sA += *(const f32x4*)&pp[(dup * 2 + 0) * 1024 + q2 * 256 + b2 * 4];
    sB += *(const f32x4*)&pp[(dup * 2 + 1) * 1024 + q2 * 256 + b2 * 4];
  }
  if (dup == 1) {
    *(f32x4*)&red[(q2 * 64 + b2) * 8] = sA;       // NI
    *(f32x4*)&red[(q2 * 64 + b2) * 8 + 4] = sB;   // NH
  }
  __syncthreads();
  if (dup == 0) {
    f32x4 ni = *(f32x4*)&red[(q2 * 64 + b2) * 8];
    f32x4 nh = *(f32x4*)&red[(q2 * 64 + b2) * 8 + 4];
    float hv[4], xv[4];
#pragma unroll
    for (int i = 0; i < 4; ++i) {
      int c = rt * 16 + q2 * 4 + i;
      float r = sigm(sA[i] + bih[c] + bhh[c]);
      float z = sigm(sB[i] + bih[kC + c] + bhh[kC + c]);
      float n = tanh_(ni[i] + bih[2 * kC + c] + r * (nh[i] + bhh[2 * kC + c]));
      float hold = h_old[c * kB + b2];
      float hn = (1.0f - z) * n + z * hold;
      hv[i] = hn;
      h_new_f32[c * kB + b2] = hn;
      float xo = xin_f32 ? (xin_f32[c * kB + b2] + hn) : hn;
      xv[i] = xo;
      if (xout_f32) xout_f32[c * kB + b2] = xo;
      if (pw) red[2048 + (q2 * 4 + i) * 64 + b2] = xo;
    }
    ushort4 hb;
    hb.x = f2bf(hv[0]); hb.y = f2bf(hv[1]); hb.z = f2bf(hv[2]); hb.w = f2bf(hv[3]);
    *(ushort4*)&h_bf16[(size_t)b2 * strideA + offA + rt * 16 + q2 * 4] = hb;
    if (x_bf16) {
      ushort4 xb;
      xb.x = f2bf(xv[0]); xb.y = f2bf(xv[1]); xb.z = f2bf(xv[2]); xb.w = f2bf(xv[3]);
      *(ushort4*)&x_bf16[(size_t)b2 * strideX + rt * 16 + q2 * 4] = xb;
    }
  }
  if (pw) {
    __syncthreads();
    int m0 = tid >> 6, bb = tid & 63;
    for (int m = m0; m < kM; m += 8) {
      const float* wrow = pw + (size_t)m * kC + rt * 16;
      float a = 0.f;
#pragma unroll
      for (int c16 = 0; c16 < 16; ++c16) a += wrow[c16] * red[2048 + c16 * 64 + bb];
      pproj[((size_t)rt * kM + m) * kB + bb] = a;
    }
  }
}

// ---- final frame (t = 511) --------------------------------------------------
__global__ __launch_bounds__(256) void k_finalize(const float* __restrict__ pproj,
    const float* __restrict__ proj_b, float* __restrict__ out) {
  int idx = blockIdx.x * 256 + threadIdx.x;
  if (idx >= kB * kM) return;
  int b = idx / kM, m = idx % kM;
  float s = proj_b[m];
#pragma unroll 8
  for (int rt = 0; rt < 64; ++rt) s += pproj[((size_t)rt * kM + m) * kB + b];
  out[(size_t)b * kT * kM + (size_t)(kT - 1) * kM + m] = s;
}

} // namespace

extern "C" void kernel_launch(void* const* d_in, const int* in_sizes, int n_in,
                              void* d_out, int out_size, void* d_ws, size_t ws_size,
                              hipStream_t stream) {
  const float* inputs   = (const float*)d_in[0];
  const float* pre_w0   = (const float*)d_in[1];
  const float* pre_b0   = (const float*)d_in[2];
  const float* pre_w1   = (const float*)d_in[3];
  const float* pre_b1   = (const float*)d_in[4];
  const float* attn_wih = (const float*)d_in[5];
  const float* attn_whh = (const float*)d_in[6];
  const float* attn_bih = (const float*)d_in[7];
  const float* attn_bhh = (const float*)d_in[8];
  const float* gru_wih  = (const float*)d_in[9];
  const float* gru_whh  = (const float*)d_in[10];
  const float* gru_bih  = (const float*)d_in[11];
  const float* gru_bhh  = (const float*)d_in[12];
  const float* proj_w   = (const float*)d_in[13];
  const float* proj_b   = (const float*)d_in[14];
  float* out = (float*)d_out;
  char* ws = (char*)d_ws;

  const size_t ATTN_MAT = (size_t)64 * 52 * 64 * 8 * 2;  // 3,407,872 B
  const size_t RES_MAT  = (size_t)64 * 64 * 64 * 8 * 2;  // 4,194,304 B
  size_t off = 0;
  unsigned short* Aattn[3];
  for (int g = 0; g < 3; ++g) { Aattn[g] = (unsigned short*)(ws + off); off += ATTN_MAT; }
  unsigned short* Ares[2][3];
  for (int l = 0; l < 2; ++l)
    for (int g = 0; g < 3; ++g) { Ares[l][g] = (unsigned short*)(ws + off); off += RES_MAT; }
  float* w0t = (float*)(ws + off); off += (size_t)kM * kH1 * 4;
  float* w1t = (float*)(ws + off); off += (size_t)kH1 * kH2 * 4;
  float* partials = (float*)(ws + off); off += (size_t)256 * 4096 * 4;   // 4 MB
  float* pproj = (float*)(ws + off); off += (size_t)64 * kM * kB * 4;    // 1.25 MB
  size_t zeroBase = off;
  int* counters = (int*)(ws + off); off += 1024;
  unsigned short* xcat0 = (unsigned short*)(ws + off); off += 2 * (size_t)kB * 1664 * 2;
  unsigned short* xcat1 = (unsigned short*)(ws + off); off += 2 * (size_t)kB * 2048 * 2;
  unsigned short* xcat2 = (unsigned short*)(ws + off); off += 2 * (size_t)kB * 2048 * 2;
  const size_t HB = (size_t)kC * kB;
  float* hA = (float*)(ws + off); off += 2 * HB * 4;
  float* h1 = (float*)(ws + off); off += 2 * HB * 4;
  float* h2 = (float*)(ws + off); off += 2 * HB * 4;
  float* x1 = (float*)(ws + off); off += HB * 4;
  if (off > ws_size) return;  // fail loud if workspace too small

  // ---- one-time per launch: weight repack + transposes + zero init ----
  for (int g = 0; g < 3; ++g)
    k_build_frags<<<16 * 52, 256, 0, stream>>>(attn_wih, 640, attn_whh, kC,
                                               g * kC, 640, 52, 64, Aattn[g]);
  for (int l = 0; l < 2; ++l) {
    const float* wih = gru_wih + (size_t)l * 3 * kC * kC;
    const float* whh = gru_whh + (size_t)l * 3 * kC * kC;
    for (int g = 0; g < 3; ++g)
      k_build_frags<<<16 * 64, 256, 0, stream>>>(wih, kC, whh, kC,
                                                 g * kC, kC, 64, 64, Ares[l][g]);
  }
  k_transpose<<<(kH1 * kM + 255) / 256, 256, 0, stream>>>(pre_w0, kH1, kM, w0t);
  k_transpose<<<(kH2 * kH1 + 255) / 256, 256, 0, stream>>>(pre_w1, kH2, kH1, w1t);
  hipMemsetAsync(ws + zeroBase, 0, off - zeroBase, stream);

  const size_t X0 = (size_t)kB * 1664;
  const size_t XC = (size_t)kB * 2048;
  const float* g_bih1 = gru_bih + 3 * kC;
  const float* g_bhh1 = gru_bhh + 3 * kC;

  for (int t = 0; t < kT; ++t) {
    int cur = t & 1, nxt = cur ^ 1;
    k_prenet<<<kB, 256, 0, stream>>>(inputs, t, pproj, proj_b,
                                     w0t, pre_b0, w1t, pre_b1,
                                     xcat0 + cur * X0, out);
    // attn GRU
    k_gru<52, 20, 208><<<256, 512, 0, stream>>>(Aattn[0], Aattn[1], Aattn[2],
        xcat0 + cur * X0, hA + cur * HB, attn_bih, attn_bhh,
        nullptr, hA + nxt * HB,
        xcat0 + nxt * X0, 1664, 640,
        xcat1 + cur * XC, 2048,
        nullptr, partials, counters, nullptr, nullptr);
    // res GRU 1
    k_gru<64, 32, 256><<<256, 512, 0, stream>>>(Ares[0][0], Ares[0][1], Ares[0][2],
        xcat1 + cur * XC, h1 + cur * HB, gru_bih, gru_bhh,
        hA + nxt * HB, h1 + nxt * HB,
        xcat1 + nxt * XC, 2048, 1024,
        xcat2 + cur * XC, 2048,
        x1, partials, counters, nullptr, nullptr);
    // res GRU 2 (+proj partials)
    k_gru<64, 32, 256><<<256, 512, 0, stream>>>(Ares[1][0], Ares[1][1], Ares[1][2],
        xcat2 + cur * XC, h2 + cur * HB, g_bih1, g_bhh1,
        x1, h2 + nxt * HB,
        xcat2 + nxt * XC, 2048, 1024,
        nullptr, 0,
        nullptr, partials, counters, proj_w, pproj);
  }
  k_finalize<<<(kB * kM + 255) / 256, 256, 0, stream>>>(pproj, proj_b, out);
}

// Round 5
// 22217.149 us; speedup vs baseline: 6.5782x; 6.5782x over previous
//
#include <hip/hip_runtime.h>
#include <cstddef>

// Decoder: B=64, T=512, I=512, H1=256, H2=128, C=1024, M=80, L=2
// Round 5: R3 structure (rt x bt blocks, 8 waves split-K within block, LDS
// reduce, in-block epilogue) + XCD swizzle so each XCD owns 8 complete row
// tiles (weights L2-resident) + proj fused into res2 epilogue as per-rt fp32
// partials, reduced by next step's prenet. 4 kernels/step.

namespace {

constexpr int kB = 64, kT = 512, kI = 512, kH1 = 256, kH2 = 128, kC = 1024, kM = 80;

typedef __attribute__((ext_vector_type(8))) __bf16 bf16x8;
typedef __attribute__((ext_vector_type(4))) float f32x4;

__device__ __forceinline__ float sigm(float x) { return 1.0f / (1.0f + __expf(-x)); }
__device__ __forceinline__ float tanh_(float x) {
  float a = fabsf(x);
  float e = __expf(-2.0f * a);
  float r = (1.0f - e) / (1.0f + e);
  return copysignf(r, x);
}
__device__ __forceinline__ unsigned short f2bf(float x) {
  unsigned u = __builtin_bit_cast(unsigned, x);
  u += 0x7fffu + ((u >> 16) & 1u);   // RNE
  return (unsigned short)(u >> 16);
}
__device__ __forceinline__ bf16x8 asbf(uint4 v) { return __builtin_bit_cast(bf16x8, v); }
__device__ __forceinline__ f32x4 mfma16(bf16x8 a, bf16x8 b, f32x4 c) {
  return __builtin_amdgcn_mfma_f32_16x16x32_bf16(a, b, c, 0, 0, 0);
}

// ---- weight repack: fp32 [row][col] -> bf16 frag order [rt][ks][lane][8] ----
__global__ __launch_bounds__(256) void k_build_frags(
    const float* __restrict__ srcA, int ldA,
    const float* __restrict__ srcB, int ldB,
    int row0, int K1, int nks, int nrt, unsigned short* __restrict__ dst) {
  int idx = blockIdx.x * 256 + threadIdx.x;
  int lane = idx & 63;
  int ks = (idx >> 6) % nks;
  int rt = idx / (64 * nks);
  if (rt >= nrt) return;
  int row = row0 + rt * 16 + (lane & 15);
  int kk = ks * 32 + ((lane >> 4) & 3) * 8;
  const float* s = (kk < K1) ? (srcA + (size_t)row * ldA + kk)
                             : (srcB + (size_t)row * ldB + (kk - K1));
  unsigned short* d = dst + ((size_t)(rt * nks + ks) * 64 + lane) * 8;
#pragma unroll
  for (int j = 0; j < 8; ++j) d[j] = f2bf(s[j]);
}

__global__ __launch_bounds__(256) void k_transpose(const float* __restrict__ src,
    int R, int Ccols, float* __restrict__ dst) {
  int i = blockIdx.x * 256 + threadIdx.x;
  if (i >= R * Ccols) return;
  int r = i / Ccols, c = i % Ccols;
  dst[c * R + r] = src[r * Ccols + c];
}

// ---- prenet (+frame reduce of step t-1): one block per batch element --------
__global__ __launch_bounds__(256) void k_prenet(
    const float* __restrict__ inputs, int t,
    const float* __restrict__ pproj,       // [64rt][80][64] partials of frame t-1
    const float* __restrict__ proj_b,
    const float* __restrict__ w0t, const float* __restrict__ b0,
    const float* __restrict__ w1t, const float* __restrict__ b1,
    unsigned short* __restrict__ xcat0_cur,  // [64][1664]
    float* __restrict__ out_frames) {
  int b = blockIdx.x, tid = threadIdx.x;
  __shared__ float sfr[kM];
  __shared__ float sh[kH1];
  __shared__ float sred[160];
  const float* feat = inputs + ((size_t)b * kT + t) * kI;
  unsigned short* dst = xcat0_cur + (size_t)b * 1664;
  float2 f2v = *(const float2*)(feat + tid * 2);
  dst[tid * 2] = f2bf(f2v.x);
  dst[tid * 2 + 1] = f2bf(f2v.y);
  if (t > 0) {
    if (tid < 160) {
      int m = tid >> 1, half = tid & 1;
      const float* pp = pproj + ((size_t)(half * 32) * kM + m) * kB + b;
      float s = 0.0f;
#pragma unroll 8
      for (int r = 0; r < 32; ++r) s += pp[(size_t)r * kM * kB];
      sred[tid] = s;
    }
    __syncthreads();
    if (tid < kM) {
      float f = proj_b[tid] + sred[tid * 2] + sred[tid * 2 + 1];
      sfr[tid] = f;
      out_frames[(size_t)b * kT * kM + (size_t)(t - 1) * kM + tid] = f;
    }
  } else {
    if (tid < kM) sfr[tid] = 0.0f;
  }
  __syncthreads();
  float acc = b0[tid];
#pragma unroll 8
  for (int m = 0; m < kM; ++m) acc = fmaf(w0t[m * kH1 + tid], sfr[m], acc);
  sh[tid] = fmaxf(acc, 0.0f);
  __syncthreads();
  if (tid < kH2) {
    float a = b1[tid];
#pragma unroll 8
    for (int k = 0; k < kH1; ++k) a = fmaf(w1t[k * kH2 + tid], sh[k], a);
    dst[512 + tid] = f2bf(fmaxf(a, 0.0f));
  }
}

// ---- GRU cell kernel --------------------------------------------------------
// 256 blocks (64 rt x 4 bt, XCD-swizzled so each XCD owns 8 complete rts),
// 512 threads = 8 waves, wave w owns ks range [w*NKS/8,(w+1)*NKS/8).
// LDS reduce + gate epilogue in-block. Optional proj-partial fusion (pw!=0).
template<int NKS, int NB, int BROW>
__global__ __launch_bounds__(512) void k_gru(
    const unsigned short* __restrict__ Ar, const unsigned short* __restrict__ Az,
    const unsigned short* __restrict__ An,
    const unsigned short* __restrict__ Bsrc,   // [64][BROW*8] bf16
    const float* __restrict__ h_old,           // [1024][64]
    const float* __restrict__ bih, const float* __restrict__ bhh,
    const float* __restrict__ xin_f32,         // nullable residual input
    float* __restrict__ h_new_f32,
    unsigned short* __restrict__ h_bf16, int hStride, int hOff,
    unsigned short* __restrict__ x_bf16, int xStride,   // nullable
    float* __restrict__ xout_f32,                       // nullable
    const float* __restrict__ pw, float* __restrict__ pproj) {  // nullable pair
  __shared__ float red[8 * 4 * 64 * 4];        // 32 KB
  __shared__ float sx[16 * 16];                // xo tile for proj fusion
  int tid = threadIdx.x;
  int lane = tid & 63, w = tid >> 6, quad = lane >> 4;
  // XCD swizzle: consecutive blockIdx round-robin across 8 XCDs; give each
  // XCD 8 complete row-tiles (all 4 bt of each) so weights stay L2-resident.
  int xcd = blockIdx.x & 7, slot = blockIdx.x >> 3;
  int rt = xcd * 8 + (slot >> 2);
  int bt = slot & 3;
  int b = bt * 16 + (lane & 15);
  int s = (w * NKS) >> 3, e = ((w + 1) * NKS) >> 3;
  const uint4* Bq = (const uint4*)Bsrc + (size_t)b * BROW + quad;
  const uint4* Arq = (const uint4*)Ar + (size_t)rt * NKS * 64 + lane;
  const uint4* Azq = (const uint4*)Az + (size_t)rt * NKS * 64 + lane;
  const uint4* Anq = (const uint4*)An + (size_t)rt * NKS * 64 + lane;
  f32x4 aR = {0.f, 0.f, 0.f, 0.f}, aZ = aR, aNI = aR, aNH = aR;
  for (int ks = s; ks < e; ++ks) {
    bf16x8 bv = asbf(Bq[ks * 4]);
    aR = mfma16(asbf(Arq[ks * 64]), bv, aR);
    aZ = mfma16(asbf(Azq[ks * 64]), bv, aZ);
    if (ks < NB) aNI = mfma16(asbf(Anq[ks * 64]), bv, aNI);
    else         aNH = mfma16(asbf(Anq[ks * 64]), bv, aNH);
  }
  *(f32x4*)(red + ((w * 4 + 0) * 64 + lane) * 4) = aR;
  *(f32x4*)(red + ((w * 4 + 1) * 64 + lane) * 4) = aZ;
  *(f32x4*)(red + ((w * 4 + 2) * 64 + lane) * 4) = aNI;
  *(f32x4*)(red + ((w * 4 + 3) * 64 + lane) * 4) = aNH;
  __syncthreads();
  if (w < 4) {
    int q = lane >> 4, bb = lane & 15;
    float R = 0.f, Z = 0.f, NI = 0.f, NH = 0.f;
#pragma unroll
    for (int ww = 0; ww < 8; ++ww) {
      int base = (ww * 4 * 64 + w * 16 + bb) * 4 + q;
      R  += red[base];
      Z  += red[base + 64 * 4];
      NI += red[base + 2 * 64 * 4];
      NH += red[base + 3 * 64 * 4];
    }
    int c = rt * 16 + w * 4 + q;
    float r = sigm(R + bih[c] + bhh[c]);
    float z = sigm(Z + bih[kC + c] + bhh[kC + c]);
    float n = tanh_(NI + bih[2 * kC + c] + r * (NH + bhh[2 * kC + c]));
    float hold = h_old[c * kB + b];
    float hn = (1.0f - z) * n + z * hold;
    h_new_f32[c * kB + b] = hn;
    h_bf16[(size_t)b * hStride + hOff + c] = f2bf(hn);
    float xo = xin_f32 ? (xin_f32[c * kB + b] + hn) : hn;
    if (x_bf16) x_bf16[(size_t)b * xStride + c] = f2bf(xo);
    if (xout_f32) xout_f32[c * kB + b] = xo;
    if (pw) sx[(w * 4 + q) * 16 + bb] = xo;   // [c16][b16]
  }
  if (pw) {
    __syncthreads();
    // proj partials: pproj[rt][m][bglobal] = proj_w[m, rt*16:+16] . xo[:, b]
    for (int idx = tid; idx < kM * 16; idx += 512) {
      int m = idx >> 4, bb = idx & 15;
      const float* wrow = pw + (size_t)m * kC + rt * 16;
      float a = 0.f;
#pragma unroll
      for (int c16 = 0; c16 < 16; ++c16) a += wrow[c16] * sx[c16 * 16 + bb];
      pproj[((size_t)rt * kM + m) * kB + bt * 16 + bb] = a;
    }
  }
}

// ---- final frame (t = 511) --------------------------------------------------
__global__ __launch_bounds__(256) void k_finalize(const float* __restrict__ pproj,
    const float* __restrict__ proj_b, float* __restrict__ out) {
  int idx = blockIdx.x * 256 + threadIdx.x;
  if (idx >= kB * kM) return;
  int b = idx / kM, m = idx % kM;
  float s = proj_b[m];
#pragma unroll 8
  for (int rt = 0; rt < 64; ++rt) s += pproj[((size_t)rt * kM + m) * kB + b];
  out[(size_t)b * kT * kM + (size_t)(kT - 1) * kM + m] = s;
}

} // namespace

extern "C" void kernel_launch(void* const* d_in, const int* in_sizes, int n_in,
                              void* d_out, int out_size, void* d_ws, size_t ws_size,
                              hipStream_t stream) {
  const float* inputs   = (const float*)d_in[0];
  const float* pre_w0   = (const float*)d_in[1];
  const float* pre_b0   = (const float*)d_in[2];
  const float* pre_w1   = (const float*)d_in[3];
  const float* pre_b1   = (const float*)d_in[4];
  const float* attn_wih = (const float*)d_in[5];
  const float* attn_whh = (const float*)d_in[6];
  const float* attn_bih = (const float*)d_in[7];
  const float* attn_bhh = (const float*)d_in[8];
  const float* gru_wih  = (const float*)d_in[9];
  const float* gru_whh  = (const float*)d_in[10];
  const float* gru_bih  = (const float*)d_in[11];
  const float* gru_bhh  = (const float*)d_in[12];
  const float* proj_w   = (const float*)d_in[13];
  const float* proj_b   = (const float*)d_in[14];
  float* out = (float*)d_out;
  char* ws = (char*)d_ws;

  const size_t ATTN_MAT = (size_t)64 * 52 * 64 * 8 * 2;  // 3,407,872 B
  const size_t RES_MAT  = (size_t)64 * 64 * 64 * 8 * 2;  // 4,194,304 B
  size_t off = 0;
  unsigned short* Aattn[3];
  for (int g = 0; g < 3; ++g) { Aattn[g] = (unsigned short*)(ws + off); off += ATTN_MAT; }
  unsigned short* Ares[2][3];
  for (int l = 0; l < 2; ++l)
    for (int g = 0; g < 3; ++g) { Ares[l][g] = (unsigned short*)(ws + off); off += RES_MAT; }
  float* w0t = (float*)(ws + off); off += (size_t)kM * kH1 * 4;
  float* w1t = (float*)(ws + off); off += (size_t)kH1 * kH2 * 4;
  float* pproj = (float*)(ws + off); off += (size_t)64 * kM * kB * 4;    // 1.25 MB
  size_t zeroBase = off;
  unsigned short* xcat0 = (unsigned short*)(ws + off); off += 2 * (size_t)kB * 1664 * 2;
  unsigned short* xcat1 = (unsigned short*)(ws + off); off += 2 * (size_t)kB * 2048 * 2;
  unsigned short* xcat2 = (unsigned short*)(ws + off); off += 2 * (size_t)kB * 2048 * 2;
  const size_t HB = (size_t)kC * kB;
  float* hA = (float*)(ws + off); off += 2 * HB * 4;
  float* h1 = (float*)(ws + off); off += 2 * HB * 4;
  float* h2 = (float*)(ws + off); off += 2 * HB * 4;
  float* x1 = (float*)(ws + off); off += HB * 4;
  if (off > ws_size) return;  // fail loud if workspace too small

  // ---- one-time per launch: weight repack + transposes + zero init ----
  for (int g = 0; g < 3; ++g)
    k_build_frags<<<16 * 52, 256, 0, stream>>>(attn_wih, 640, attn_whh, kC,
                                               g * kC, 640, 52, 64, Aattn[g]);
  for (int l = 0; l < 2; ++l) {
    const float* wih = gru_wih + (size_t)l * 3 * kC * kC;
    const float* whh = gru_whh + (size_t)l * 3 * kC * kC;
    for (int g = 0; g < 3; ++g)
      k_build_frags<<<16 * 64, 256, 0, stream>>>(wih, kC, whh, kC,
                                                 g * kC, kC, 64, 64, Ares[l][g]);
  }
  k_transpose<<<(kH1 * kM + 255) / 256, 256, 0, stream>>>(pre_w0, kH1, kM, w0t);
  k_transpose<<<(kH2 * kH1 + 255) / 256, 256, 0, stream>>>(pre_w1, kH2, kH1, w1t);
  hipMemsetAsync(ws + zeroBase, 0, off - zeroBase, stream);

  const size_t X0 = (size_t)kB * 1664;
  const size_t XC = (size_t)kB * 2048;
  const float* g_bih1 = gru_bih + 3 * kC;
  const float* g_bhh1 = gru_bhh + 3 * kC;

  for (int t = 0; t < kT; ++t) {
    int cur = t & 1, nxt = cur ^ 1;
    k_prenet<<<kB, 256, 0, stream>>>(inputs, t, pproj, proj_b,
                                     w0t, pre_b0, w1t, pre_b1,
                                     xcat0 + cur * X0, out);
    // attn GRU: B = xcat0[cur] (feat|p|h); h -> xcat0[nxt]+640, xcat1[cur] x-slot
    k_gru<52, 20, 208><<<256, 512, 0, stream>>>(Aattn[0], Aattn[1], Aattn[2],
        xcat0 + cur * X0, hA + cur * HB, attn_bih, attn_bhh,
        nullptr, hA + nxt * HB,
        xcat0 + nxt * X0, 1664, 640,
        xcat1 + cur * XC, 2048,
        nullptr, nullptr, nullptr);
    // res GRU 1: B = xcat1[cur] (x|h1); h1 -> xcat1[nxt]+1024; x1 -> xcat2[cur]
    k_gru<64, 32, 256><<<256, 512, 0, stream>>>(Ares[0][0], Ares[0][1], Ares[0][2],
        xcat1 + cur * XC, h1 + cur * HB, gru_bih, gru_bhh,
        hA + nxt * HB, h1 + nxt * HB,
        xcat1 + nxt * XC, 2048, 1024,
        xcat2 + cur * XC, 2048,
        x1, nullptr, nullptr);
    // res GRU 2 (+proj partials): B = xcat2[cur] (x1|h2); h2 -> xcat2[nxt]+1024
    k_gru<64, 32, 256><<<256, 512, 0, stream>>>(Ares[1][0], Ares[1][1], Ares[1][2],
        xcat2 + cur * XC, h2 + cur * HB, g_bih1, g_bhh1,
        x1, h2 + nxt * HB,
        xcat2 + nxt * XC, 2048, 1024,
        nullptr, 0,
        nullptr, proj_w, pproj);
  }
  k_finalize<<<(kB * kM + 255) / 256, 256, 0, stream>>>(pproj, proj_b, out);
}